// Round 8
// baseline (404.202 us; speedup 1.0000x reference)
//
#include <hip/hip_runtime.h>
#include <hip/hip_bf16.h>
#include <math.h>

// SGC: out = log_softmax( S^2 X W^T + b ), S = D^-1/2 (A+I) D^-1/2
// t0 = dis .* (X W^T) in bf16 (pre-scaled 80 B rows). Each hop runs in TWO
// passes split by source half so the gather working set is 4 MB = one XCD L2:
//   phase A: partial[d] = t[d] + sum_{src<50000} t[src]      (f32 partials)
//   phase B: out[d] = dd^2*(partial[d] + sum_{src>=50000} t[src])
// CSR built via two-level bucketed counting sort; p4 also partitions each
// dst's src list into lo/hi halves (mid[] array).

#define N_NODES 100000
#define N_FEAT  128
#define N_CLASS 40
#define HALF_N  50000         // src split point (t rows [0,50000) = 4 MB)

#define NB      512           // fine dst buckets
#define RANGE   196           // dst ids per fine bucket (512*196 = 100352)
#define NC      64            // coarse buckets
#define RANGE_C 1568          // 8*RANGE
#define CAP     7168          // fine records per bucket in LDS
#define CCAP    53248         // coarse region capacity (mean 50000 + ~14 sigma)
#define P3AGRID 1024

typedef __attribute__((ext_vector_type(8))) short short8;   // 8 bf16 (4 VGPRs)
typedef __attribute__((ext_vector_type(4))) float floatx4;  // MFMA C/D

// ---------------------------------------------------------------------------
// Detect int32 vs int64 edge_index words; zero counters. 1 block x 512.
__global__ void detect_zero_kernel(const int* __restrict__ ei, int* __restrict__ flag,
                                   int* __restrict__ bucketCount,
                                   int* __restrict__ coarseCnt) {
    int t = threadIdx.x;
    if (t < NB) bucketCount[t] = 0;
    if (t < NC) coarseCnt[t] = 0;
    if (t < 64) {
        int nz = (ei[2 * t + 1] != 0) ? 1 : 0;
        unsigned long long b = __ballot(nz);
        if (t == 0) *flag = (b == 0ull) ? 1 : 0;   // 1 => int64 layout
    }
}

__device__ __forceinline__ int edge_word(const int* ei, int elem, int is64) {
    return is64 ? ei[2 * elem] : ei[elem];
}

// P3a: scatter packed records (dstLocalCoarse<<17 | src) into per-block dense
// runs within 64 coarse regions; simultaneously build the 512-fine histogram.
__global__ __launch_bounds__(256) void p3a_scatter(
    const int* __restrict__ ei, int E, const int* __restrict__ flag,
    int* __restrict__ bucketCount, int* __restrict__ coarseCnt,
    unsigned int* __restrict__ tmpc)
{
    __shared__ int hf[NB];
    __shared__ int hc[NC];
    __shared__ int basec[NC];
    __shared__ int curc[NC];
    int t = threadIdx.x;
    for (int i = t; i < NB; i += 256) hf[i] = 0;
    if (t < NC) hc[t] = 0;
    __syncthreads();
    int is64 = *flag;
    int per = (E + gridDim.x - 1) / gridDim.x;
    int e0 = blockIdx.x * per;
    int e1 = min(E, e0 + per);
    for (int e = e0 + t; e < e1; e += 256) {
        int c = edge_word(ei, E + e, is64);
        atomicAdd(&hf[c / RANGE], 1);
        atomicAdd(&hc[c / RANGE_C], 1);
    }
    __syncthreads();
    if (t < NC) {
        basec[t] = hc[t] ? atomicAdd(&coarseCnt[t], hc[t]) : 0;
        curc[t] = 0;
    }
    for (int i = t; i < NB; i += 256)
        if (hf[i]) atomicAdd(&bucketCount[i], hf[i]);
    __syncthreads();
    for (int e = e0 + t; e < e1; e += 256) {
        int c = edge_word(ei, E + e, is64);
        int r = edge_word(ei, e, is64);
        int cb = c / RANGE_C;
        int p = basec[cb] + atomicAdd(&curc[cb], 1);
        if (p < CCAP)
            tmpc[(size_t)cb * CCAP + p] = ((unsigned)(c - cb * RANGE_C) << 17) | (unsigned)r;
    }
}

// P2: scan fine counts -> bucketStart/bucketCursor; starts[N]=E, mid[N] n/a.
__global__ __launch_bounds__(NB) void p2_scan(
    const int* __restrict__ bucketCount, int* __restrict__ bucketStart,
    int* __restrict__ bucketCursor, int* __restrict__ starts, int E)
{
    __shared__ int s[NB];
    int t = threadIdx.x;
    int v = bucketCount[t];
    s[t] = v;
    __syncthreads();
    for (int o = 1; o < NB; o <<= 1) {
        int y = (t >= o) ? s[t - o] : 0;
        __syncthreads();
        s[t] += y;
        __syncthreads();
    }
    int incl = s[t], excl = incl - v;
    bucketStart[t] = excl;
    bucketCursor[t] = excl;
    if (t == NB - 1) { bucketStart[NB] = incl; starts[N_NODES] = E; }
}

// P3b: 8 blocks per coarse bucket; re-scatter into the 8 fine buckets.
__global__ __launch_bounds__(256) void p3b_scatter(
    const unsigned int* __restrict__ tmpc, const int* __restrict__ coarseCnt,
    int* __restrict__ bucketCursor, unsigned int* __restrict__ tmp)
{
    __shared__ int fh[8];
    __shared__ int fb[8];
    __shared__ int fc[8];
    int cb = blockIdx.x >> 3;
    int j = blockIdx.x & 7;
    int t = threadIdx.x;
    int cnt = coarseCnt[cb];
    if (cnt > CCAP) cnt = CCAP;
    int chunk = (cnt + 7) >> 3;
    int r0 = j * chunk;
    int r1 = min(cnt, r0 + chunk);
    if (t < 8) fh[t] = 0;
    __syncthreads();
    const unsigned int* rec = tmpc + (size_t)cb * CCAP;
    for (int i = r0 + t; i < r1; i += 256) {
        int dlc = (int)(rec[i] >> 17);
        atomicAdd(&fh[dlc / RANGE], 1);
    }
    __syncthreads();
    if (t < 8) {
        fb[t] = fh[t] ? atomicAdd(&bucketCursor[cb * 8 + t], fh[t]) : 0;
        fc[t] = 0;
    }
    __syncthreads();
    for (int i = r0 + t; i < r1; i += 256) {
        unsigned v = rec[i];
        int dlc = (int)(v >> 17);
        unsigned src = v & 0x1FFFFu;
        int fi = dlc / RANGE;
        int dlf = dlc - fi * RANGE;
        int p = fb[fi] + atomicAdd(&fc[fi], 1);
        tmp[p] = ((unsigned)dlf << 24) | src;
    }
}

// P4: per-fine-bucket LDS counting sort; within each dst segment, srcs are
// partitioned lo (src<HALF_N) then hi. Emits starts, mid, dis, srcs.
__global__ __launch_bounds__(256) void p4_sort(
    const unsigned int* __restrict__ tmp, const int* __restrict__ bucketStart,
    int* __restrict__ starts, int* __restrict__ mid,
    float* __restrict__ dis, int* __restrict__ srcs, int N)
{
    __shared__ unsigned int rec[CAP];
    __shared__ int srt[CAP];
    __shared__ int hlo[256];
    __shared__ int hhi[256];
    __shared__ int sc[256];
    __shared__ int clo[256];
    __shared__ int chi[256];
    int b = blockIdx.x, t = threadIdx.x;
    int g0 = b * RANGE;
    int gcnt = N - g0;
    if (gcnt > RANGE) gcnt = RANGE;
    if (gcnt < 0) gcnt = 0;
    int base = bucketStart[b];
    int n = bucketStart[b + 1] - base;
    hlo[t] = 0; hhi[t] = 0;
    __syncthreads();
    bool inl = (n <= CAP);
    for (int i = t; i < n; i += 256) {
        unsigned v = tmp[base + i];
        if (inl) rec[i] = v;
        int dl = v >> 24;
        if ((v & 0xFFFFFFu) >= (unsigned)HALF_N) atomicAdd(&hhi[dl], 1);
        else                                     atomicAdd(&hlo[dl], 1);
    }
    __syncthreads();
    int lo = hlo[t], hi = hhi[t], tot = lo + hi;
    sc[t] = tot;
    __syncthreads();
    for (int o = 1; o < 256; o <<= 1) {
        int y = (t >= o) ? sc[t - o] : 0;
        __syncthreads();
        sc[t] += y;
        __syncthreads();
    }
    int excl = sc[t] - tot;
    if (t < gcnt) {
        starts[g0 + t] = base + excl;
        mid[g0 + t] = base + excl + lo;
        dis[g0 + t] = rsqrtf((float)(tot + 1));   // +1 self-loop
    }
    clo[t] = excl;
    chi[t] = excl + lo;
    __syncthreads();
    if (inl) {
        for (int i = t; i < n; i += 256) {
            unsigned v = rec[i];
            int dl = v >> 24;
            unsigned s = v & 0xFFFFFFu;
            int p = (s >= (unsigned)HALF_N) ? atomicAdd(&chi[dl], 1)
                                            : atomicAdd(&clo[dl], 1);
            srt[p] = (int)s;
        }
        __syncthreads();
        for (int i = t; i < n; i += 256) srcs[base + i] = srt[i];
    } else {
        for (int i = t; i < n; i += 256) {
            unsigned v = tmp[base + i];
            int dl = v >> 24;
            unsigned s = v & 0xFFFFFFu;
            int p = (s >= (unsigned)HALF_N) ? atomicAdd(&chi[dl], 1)
                                            : atomicAdd(&clo[dl], 1);
            srcs[base + p] = (int)s;
        }
    }
}

// ---------------------------------------------------------------------------
__device__ __forceinline__ unsigned short f2bf(float f) {   // RTN f32 -> bf16
    unsigned u = __float_as_uint(f);
    unsigned r = u + 0x7FFFu + ((u >> 16) & 1u);
    return (unsigned short)(r >> 16);
}
__device__ __forceinline__ float bf2f(unsigned short u) {
    return __uint_as_float(((unsigned)u) << 16);
}

// t0 = dis .* (X @ W^T), bf16, row stride 40 (80 B). One wave per 16 nodes.
__global__ __launch_bounds__(256) void transform_mfma(
    const float* __restrict__ x, const float* __restrict__ W,
    const float* __restrict__ dis, unsigned short* __restrict__ t0, int N)
{
    __shared__ uint4 Wl[3 * 4 * 64];        // B frags, bf16-packed: 12 KiB
    int t = threadIdx.x;
    for (int i = t; i < 3 * 4 * 64; i += 256) {
        int lane = i & 63;
        int kc = (i >> 6) & 3;
        int nt = i >> 8;
        int n = nt * 16 + (lane & 15);
        int k = kc * 32 + (lane >> 4) * 8;
        union { unsigned short s[8]; uint4 v; } u;
        #pragma unroll
        for (int j = 0; j < 8; ++j)
            u.s[j] = (n < N_CLASS) ? f2bf(W[n * N_FEAT + k + j]) : (unsigned short)0;
        Wl[i] = u.v;
    }
    __syncthreads();
    int wave = (blockIdx.x * blockDim.x + threadIdx.x) >> 6;
    int lane = threadIdx.x & 63;
    int ntile = (N + 15) / 16;
    if (wave >= ntile) return;
    int m = lane & 15, quad = lane >> 4;
    int row = wave * 16 + m;
    const short8* Wf = reinterpret_cast<const short8*>(Wl);
    floatx4 acc0 = {0.f, 0.f, 0.f, 0.f}, acc1 = acc0, acc2 = acc0;
    #pragma unroll
    for (int kc = 0; kc < 4; ++kc) {
        const float4* xr = reinterpret_cast<const float4*>(
            x + (size_t)row * N_FEAT + kc * 32 + quad * 8);
        float4 a0 = xr[0], a1 = xr[1];
        short8 af;
        af[0] = f2bf(a0.x); af[1] = f2bf(a0.y); af[2] = f2bf(a0.z); af[3] = f2bf(a0.w);
        af[4] = f2bf(a1.x); af[5] = f2bf(a1.y); af[6] = f2bf(a1.z); af[7] = f2bf(a1.w);
        short8 b0 = Wf[(0 * 4 + kc) * 64 + lane];
        short8 b1 = Wf[(1 * 4 + kc) * 64 + lane];
        short8 b2 = Wf[(2 * 4 + kc) * 64 + lane];
        acc0 = __builtin_amdgcn_mfma_f32_16x16x32_bf16(af, b0, acc0, 0, 0, 0);
        acc1 = __builtin_amdgcn_mfma_f32_16x16x32_bf16(af, b1, acc1, 0, 0, 0);
        acc2 = __builtin_amdgcn_mfma_f32_16x16x32_bf16(af, b2, acc2, 0, 0, 0);
    }
    #pragma unroll
    for (int r = 0; r < 4; ++r) {
        int rw = wave * 16 + quad * 4 + r;
        float ds = dis[rw];
        unsigned short* tr = t0 + (size_t)rw * N_CLASS;
        tr[m] = f2bf(ds * acc0[r]);
        tr[16 + m] = f2bf(ds * acc1[r]);
        if (m < 8) tr[32 + m] = f2bf(ds * acc2[r]);
    }
}

// --- gather helpers: 6 edges/iter, 10 lanes x ushort4 per edge row ----------
__device__ __forceinline__ void gather_edges(
    const unsigned short* __restrict__ tin, const int* __restrict__ srcs,
    int e0, int e1, int g, int sl,
    float& a0, float& a1, float& a2, float& a3)
{
    int cnt = e1 - e0;
    int full = cnt / 6, rem = cnt - full * 6;
    int e = e0 + ((g < 6) ? g : 0);         // lanes 60-63 ghost group 0, unread
    for (int it = 0; it < full; ++it) {
        int s = srcs[e];
        ushort4 r = *reinterpret_cast<const ushort4*>(tin + (size_t)s * N_CLASS + sl * 4);
        a0 += bf2f(r.x); a1 += bf2f(r.y); a2 += bf2f(r.z); a3 += bf2f(r.w);
        e += 6;
    }
    if (g < rem) {                          // rem<6 excludes ghosts
        int s = srcs[e];
        ushort4 r = *reinterpret_cast<const ushort4*>(tin + (size_t)s * N_CLASS + sl * 4);
        a0 += bf2f(r.x); a1 += bf2f(r.y); a2 += bf2f(r.z); a3 += bf2f(r.w);
    }
}

__device__ __forceinline__ void fold6(
    int lane, float& a0, float& a1, float& a2, float& a3)
{
    a0 += __shfl(a0, lane + 30); a1 += __shfl(a1, lane + 30);
    a2 += __shfl(a2, lane + 30); a3 += __shfl(a3, lane + 30);
    float u0 = __shfl(a0, lane + 10), v0 = __shfl(a0, lane + 20);
    float u1 = __shfl(a1, lane + 10), v1 = __shfl(a1, lane + 20);
    float u2 = __shfl(a2, lane + 10), v2 = __shfl(a2, lane + 20);
    float u3 = __shfl(a3, lane + 10), v3 = __shfl(a3, lane + 20);
    a0 += u0 + v0; a1 += u1 + v1; a2 += u2 + v2; a3 += u3 + v3;
}

// Phase A: partial[d] = t[d] + sum_{lo edges} t[src]  (f32, gathers in 4 MB)
__global__ __launch_bounds__(256) void prop_lo(
    const unsigned short* __restrict__ tin, float* __restrict__ partial,
    const int* __restrict__ starts, const int* __restrict__ mid,
    const int* __restrict__ srcs, int N)
{
    int wave = (blockIdx.x * blockDim.x + threadIdx.x) >> 6;
    int lane = threadIdx.x & 63;
    if (wave >= N) return;
    int d = wave;
    int g = lane / 10, sl = lane - g * 10;
    float a0 = 0.f, a1 = 0.f, a2 = 0.f, a3 = 0.f;
    if (g == 0) {                           // self term
        ushort4 r = *reinterpret_cast<const ushort4*>(tin + (size_t)d * N_CLASS + sl * 4);
        a0 = bf2f(r.x); a1 = bf2f(r.y); a2 = bf2f(r.z); a3 = bf2f(r.w);
    }
    gather_edges(tin, srcs, starts[d], mid[d], g, sl, a0, a1, a2, a3);
    fold6(lane, a0, a1, a2, a3);
    if (lane < 10)
        *reinterpret_cast<float4*>(partial + (size_t)d * N_CLASS + lane * 4) =
            make_float4(a0, a1, a2, a3);
}

// Phase B (mid hop): tout[d] = bf16( dd^2 * (partial[d] + sum_{hi} t[src]) )
__global__ __launch_bounds__(256) void prop_hi_mid(
    const unsigned short* __restrict__ tin, const float* __restrict__ partial,
    unsigned short* __restrict__ tout,
    const int* __restrict__ starts, const int* __restrict__ mid,
    const int* __restrict__ srcs, const float* __restrict__ dis, int N)
{
    int wave = (blockIdx.x * blockDim.x + threadIdx.x) >> 6;
    int lane = threadIdx.x & 63;
    if (wave >= N) return;
    int d = wave;
    int g = lane / 10, sl = lane - g * 10;
    float a0 = 0.f, a1 = 0.f, a2 = 0.f, a3 = 0.f;
    if (g == 0) {
        float4 p = *reinterpret_cast<const float4*>(partial + (size_t)d * N_CLASS + sl * 4);
        a0 = p.x; a1 = p.y; a2 = p.z; a3 = p.w;
    }
    gather_edges(tin, srcs, mid[d], starts[d + 1], g, sl, a0, a1, a2, a3);
    fold6(lane, a0, a1, a2, a3);
    if (lane < 10) {
        float dd = dis[d];
        float sc = dd * dd;
        ushort4 o;
        o.x = f2bf(sc * a0); o.y = f2bf(sc * a1);
        o.z = f2bf(sc * a2); o.w = f2bf(sc * a3);
        *reinterpret_cast<ushort4*>(tout + (size_t)d * N_CLASS + lane * 4) = o;
    }
}

// Phase B (final hop): logits + bias + log_softmax -> out (f32)
__global__ __launch_bounds__(256) void prop_hi_final(
    const unsigned short* __restrict__ tin, const float* __restrict__ partial,
    float* __restrict__ out,
    const int* __restrict__ starts, const int* __restrict__ mid,
    const int* __restrict__ srcs, const float* __restrict__ dis,
    const float* __restrict__ bias, int N)
{
    int wave = (blockIdx.x * blockDim.x + threadIdx.x) >> 6;
    int lane = threadIdx.x & 63;
    if (wave >= N) return;
    int d = wave;
    int g = lane / 10, sl = lane - g * 10;
    float a0 = 0.f, a1 = 0.f, a2 = 0.f, a3 = 0.f;
    if (g == 0) {
        float4 p = *reinterpret_cast<const float4*>(partial + (size_t)d * N_CLASS + sl * 4);
        a0 = p.x; a1 = p.y; a2 = p.z; a3 = p.w;
    }
    gather_edges(tin, srcs, mid[d], starts[d + 1], g, sl, a0, a1, a2, a3);
    fold6(lane, a0, a1, a2, a3);
    float dd = dis[d];
    float4 b4 = reinterpret_cast<const float4*>(bias)[sl];   // sl<10 always
    float v0_ = dd * a0 + b4.x, v1_ = dd * a1 + b4.y;
    float v2_ = dd * a2 + b4.z, v3_ = dd * a3 + b4.w;
    float mx = (lane < 10) ? fmaxf(fmaxf(v0_, v1_), fmaxf(v2_, v3_)) : -INFINITY;
    #pragma unroll
    for (int o = 8; o; o >>= 1) mx = fmaxf(mx, __shfl_xor(mx, o));
    float sum = (lane < 10)
        ? (expf(v0_ - mx) + expf(v1_ - mx) + expf(v2_ - mx) + expf(v3_ - mx)) : 0.f;
    #pragma unroll
    for (int o = 8; o; o >>= 1) sum += __shfl_xor(sum, o);
    if (lane < 10) {
        float ls = mx + logf(sum);
        float4 o4 = make_float4(v0_ - ls, v1_ - ls, v2_ - ls, v3_ - ls);
        reinterpret_cast<float4*>(out + (size_t)d * N_CLASS)[lane] = o4;
    }
}

// ---------------------------------------------------------------------------
extern "C" void kernel_launch(void* const* d_in, const int* in_sizes, int n_in,
                              void* d_out, int out_size, void* d_ws, size_t ws_size,
                              hipStream_t stream) {
    const float* feature = (const float*)d_in[0];   // [N, 128]
    const float* weight  = (const float*)d_in[1];   // [40, 128]
    const float* bias    = (const float*)d_in[2];   // [40]
    const int*   ei      = (const int*)d_in[3];     // [2, E] (int32 or int64 words)
    const int N = N_NODES;
    const int E = in_sizes[3] / 2;

    size_t off = 0;
    auto take = [&](size_t bytes) { size_t o = off; off += (bytes + 255) & ~(size_t)255; return o; };
    char* ws = (char*)d_ws;
    int*   flag      = (int*)  (ws + take(4));
    int*   bCount    = (int*)  (ws + take((size_t)NB * 4));
    int*   bStart    = (int*)  (ws + take((size_t)(NB + 1) * 4));
    int*   bCursor   = (int*)  (ws + take((size_t)NB * 4));
    int*   coarseCnt = (int*)  (ws + take((size_t)NC * 4));
    int*   starts    = (int*)  (ws + take((size_t)(N + 1) * 4));
    int*   mid       = (int*)  (ws + take((size_t)N * 4));
    float* dis       = (float*)(ws + take((size_t)N * 4));
    // srcs region also hosts tmpc (coarse records): tmpc dead before p4 writes srcs
    size_t srcsBytes = (size_t)E * 4;
    size_t tmpcBytes = (size_t)NC * CCAP * 4;
    size_t bigBytes = srcsBytes > tmpcBytes ? srcsBytes : tmpcBytes;
    char* bigBase = ws + take(bigBytes);
    int* srcs = (int*)bigBase;
    unsigned int* tmpc = (unsigned int*)bigBase;
    // t0+t1 (16 MB contiguous) also host tmp (fine records, E*4 = 12.8 MB)
    unsigned short* t0 = (unsigned short*)(ws + take((size_t)N * N_CLASS * 2));
    unsigned short* t1 = (unsigned short*)(ws + take((size_t)N * N_CLASS * 2));
    unsigned int* tmp = (unsigned int*)t0;
    float* partial = (float*)(ws + take((size_t)N * N_CLASS * 4));   // 16 MB f32

    // --- build CSR (two-level bucketed counting sort + lo/hi partition) ---
    detect_zero_kernel<<<1, 512, 0, stream>>>(ei, flag, bCount, coarseCnt);
    p3a_scatter<<<P3AGRID, 256, 0, stream>>>(ei, E, flag, bCount, coarseCnt, tmpc);
    p2_scan<<<1, NB, 0, stream>>>(bCount, bStart, bCursor, starts, E);
    p3b_scatter<<<NC * 8, 256, 0, stream>>>(tmpc, coarseCnt, bCursor, tmp);
    p4_sort<<<NB, 256, 0, stream>>>(tmp, bStart, starts, mid, dis, srcs, N);

    // --- transform (MFMA, pre-scaled bf16 rows) then 2 hops x 2 passes ---
    const int ntile = (N + 15) / 16;
    const int tblocks = (ntile * 64 + 255) / 256;
    transform_mfma<<<tblocks, 256, 0, stream>>>(feature, weight, dis, t0, N);
    const int nodeBlocks = (N * 64 + 255) / 256;           // one wave per node
    // hop 1: t0 -> t1
    prop_lo<<<nodeBlocks, 256, 0, stream>>>(t0, partial, starts, mid, srcs, N);
    prop_hi_mid<<<nodeBlocks, 256, 0, stream>>>(t0, partial, t1, starts, mid, srcs, dis, N);
    // hop 2: t1 -> logits + softmax
    prop_lo<<<nodeBlocks, 256, 0, stream>>>(t1, partial, starts, mid, srcs, N);
    prop_hi_final<<<nodeBlocks, 256, 0, stream>>>(t1, partial, (float*)d_out,
                                                  starts, mid, srcs, dis, bias, N);
}

// Round 9
// 333.794 us; speedup vs baseline: 1.2109x; 1.2109x over previous
//
#include <hip/hip_runtime.h>
#include <hip/hip_bf16.h>
#include <math.h>

// SGC: out = log_softmax( S^2 X W^T + b ), S = D^-1/2 (A+I) D^-1/2
// t0 = dis .* (X W^T) in bf16 (pre-scaled 80 B rows). One wave per dst node;
// gather = 12 groups x 5 lanes x ushort8 (one 16B load covers 1/5 row),
// 24-edge unmasked main loop (2 gathers in flight) + masked 12-edge tail.
// CSR via two-level bucketed counting sort with power-of-2 bucket ranges.

#define N_NODES 100000
#define N_FEAT  128
#define N_CLASS 40

#define RANGE   256           // dsts per fine bucket (pow2: dst>>8)
#define NBALLOC 512
#define NBUSED  391           // ceil(100000/256)
#define RANGE_C 2048          // dsts per coarse bucket (dst>>11)
#define NCALLOC 64
#define NCUSED  49            // ceil(100000/2048)
#define CAP     8704          // fine bucket LDS cap (mean 8192 + ~5.7 sigma)
#define CCAP    67072         // coarse region cap (mean 65536 + ~6 sigma)
#define P3AGRID 1024

typedef __attribute__((ext_vector_type(8))) short short8;   // 8 bf16 (4 VGPRs)
typedef __attribute__((ext_vector_type(4))) float floatx4;  // MFMA C/D

// ---------------------------------------------------------------------------
// Detect int32 vs int64 edge_index words; zero counters. 1 block x 512.
__global__ void detect_zero_kernel(const int* __restrict__ ei, int* __restrict__ flag,
                                   int* __restrict__ bucketCount,
                                   int* __restrict__ coarseCnt) {
    int t = threadIdx.x;
    if (t < NBALLOC) bucketCount[t] = 0;
    if (t < NCALLOC) coarseCnt[t] = 0;
    if (t < 64) {
        int nz = (ei[2 * t + 1] != 0) ? 1 : 0;
        unsigned long long b = __ballot(nz);
        if (t == 0) *flag = (b == 0ull) ? 1 : 0;   // 1 => int64 layout
    }
}

__device__ __forceinline__ int edge_word(const int* ei, int elem, int is64) {
    return is64 ? ei[2 * elem] : ei[elem];
}

// P3a: scatter packed records (dstLocalCoarse<<17 | src) into per-block dense
// runs within coarse regions; simultaneously build the fine histogram.
__global__ __launch_bounds__(256) void p3a_scatter(
    const int* __restrict__ ei, int E, const int* __restrict__ flag,
    int* __restrict__ bucketCount, int* __restrict__ coarseCnt,
    unsigned int* __restrict__ tmpc)
{
    __shared__ int hf[NBALLOC];
    __shared__ int hc[NCALLOC];
    __shared__ int basec[NCALLOC];
    __shared__ int curc[NCALLOC];
    int t = threadIdx.x;
    for (int i = t; i < NBALLOC; i += 256) hf[i] = 0;
    if (t < NCALLOC) hc[t] = 0;
    __syncthreads();
    int is64 = *flag;
    int per = (E + gridDim.x - 1) / gridDim.x;
    int e0 = blockIdx.x * per;
    int e1 = min(E, e0 + per);
    for (int e = e0 + t; e < e1; e += 256) {
        int c = edge_word(ei, E + e, is64);
        atomicAdd(&hf[c >> 8], 1);
        atomicAdd(&hc[c >> 11], 1);
    }
    __syncthreads();
    if (t < NCALLOC) {
        basec[t] = hc[t] ? atomicAdd(&coarseCnt[t], hc[t]) : 0;
        curc[t] = 0;
    }
    for (int i = t; i < NBALLOC; i += 256)
        if (hf[i]) atomicAdd(&bucketCount[i], hf[i]);
    __syncthreads();
    for (int e = e0 + t; e < e1; e += 256) {
        int c = edge_word(ei, E + e, is64);
        int r = edge_word(ei, e, is64);
        int cb = c >> 11;
        int p = basec[cb] + atomicAdd(&curc[cb], 1);
        if (p < CCAP)
            tmpc[(size_t)cb * CCAP + p] = ((unsigned)(c & 2047) << 17) | (unsigned)r;
    }
}

// P2: scan fine counts -> bucketStart/bucketCursor; starts[N]=E.
__global__ __launch_bounds__(NBALLOC) void p2_scan(
    const int* __restrict__ bucketCount, int* __restrict__ bucketStart,
    int* __restrict__ bucketCursor, int* __restrict__ starts, int E)
{
    __shared__ int s[NBALLOC];
    int t = threadIdx.x;
    int v = bucketCount[t];
    s[t] = v;
    __syncthreads();
    for (int o = 1; o < NBALLOC; o <<= 1) {
        int y = (t >= o) ? s[t - o] : 0;
        __syncthreads();
        s[t] += y;
        __syncthreads();
    }
    int incl = s[t], excl = incl - v;
    bucketStart[t] = excl;
    bucketCursor[t] = excl;
    if (t == NBALLOC - 1) { bucketStart[NBALLOC] = incl; starts[N_NODES] = E; }
}

// P3b: 8 blocks per coarse bucket; re-scatter into its 8 fine buckets.
__global__ __launch_bounds__(256) void p3b_scatter(
    const unsigned int* __restrict__ tmpc, const int* __restrict__ coarseCnt,
    int* __restrict__ bucketCursor, unsigned int* __restrict__ tmp)
{
    __shared__ int fh[8];
    __shared__ int fb[8];
    __shared__ int fc[8];
    int cb = blockIdx.x >> 3;
    int j = blockIdx.x & 7;
    int t = threadIdx.x;
    int cnt = coarseCnt[cb];
    if (cnt > CCAP) cnt = CCAP;
    int chunk = (cnt + 7) >> 3;
    int r0 = j * chunk;
    int r1 = min(cnt, r0 + chunk);
    if (t < 8) fh[t] = 0;
    __syncthreads();
    const unsigned int* rec = tmpc + (size_t)cb * CCAP;
    for (int i = r0 + t; i < r1; i += 256) {
        int dlc = (int)(rec[i] >> 17);
        atomicAdd(&fh[dlc >> 8], 1);
    }
    __syncthreads();
    if (t < 8) {
        fb[t] = fh[t] ? atomicAdd(&bucketCursor[cb * 8 + t], fh[t]) : 0;
        fc[t] = 0;
    }
    __syncthreads();
    for (int i = r0 + t; i < r1; i += 256) {
        unsigned v = rec[i];
        int dlc = (int)(v >> 17);
        unsigned src = v & 0x1FFFFu;
        int fi = dlc >> 8;
        int dlf = dlc & 255;
        int p = fb[fi] + atomicAdd(&fc[fi], 1);
        tmp[p] = ((unsigned)dlf << 24) | src;
    }
}

// P4: per-fine-bucket LDS counting sort -> starts, dis, srcsB (byte offsets,
// src*80, coalesced). No rec[] cache: tmp is read twice (streaming).
__global__ __launch_bounds__(256) void p4_sort(
    const unsigned int* __restrict__ tmp, const int* __restrict__ bucketStart,
    int* __restrict__ starts, float* __restrict__ dis, int* __restrict__ srcsB, int N)
{
    __shared__ int srt[CAP];
    __shared__ int hist[256];
    __shared__ int sc[256];
    __shared__ int cur[256];
    int b = blockIdx.x, t = threadIdx.x;
    int g0 = b * RANGE;
    int gcnt = N - g0;
    if (gcnt > RANGE) gcnt = RANGE;
    int base = bucketStart[b];
    int n = bucketStart[b + 1] - base;
    hist[t] = 0;
    __syncthreads();
    for (int i = t; i < n; i += 256)
        atomicAdd(&hist[tmp[base + i] >> 24], 1);
    __syncthreads();
    int hv = hist[t];
    sc[t] = hv;
    __syncthreads();
    for (int o = 1; o < 256; o <<= 1) {
        int y = (t >= o) ? sc[t - o] : 0;
        __syncthreads();
        sc[t] += y;
        __syncthreads();
    }
    int excl = sc[t] - hv;
    if (t < gcnt) {
        starts[g0 + t] = base + excl;
        dis[g0 + t] = rsqrtf((float)(hv + 1));   // +1 self-loop
    }
    cur[t] = excl;
    __syncthreads();
    if (n <= CAP) {
        for (int i = t; i < n; i += 256) {
            unsigned v = tmp[base + i];
            int p = atomicAdd(&cur[v >> 24], 1);
            srt[p] = (int)(v & 0xFFFFFFu) * 80;   // pre-scaled byte offset
        }
        __syncthreads();
        for (int i = t; i < n; i += 256) srcsB[base + i] = srt[i];
    } else {
        // overflow fallback (statistically never taken)
        for (int i = t; i < n; i += 256) {
            unsigned v = tmp[base + i];
            int p = atomicAdd(&cur[v >> 24], 1);
            srcsB[base + p] = (int)(v & 0xFFFFFFu) * 80;
        }
    }
}

// ---------------------------------------------------------------------------
__device__ __forceinline__ unsigned short f2bf(float f) {   // RTN f32 -> bf16
    unsigned u = __float_as_uint(f);
    unsigned r = u + 0x7FFFu + ((u >> 16) & 1u);
    return (unsigned short)(r >> 16);
}
__device__ __forceinline__ float bfl(unsigned w) {   // low bf16 of dword
    return __uint_as_float(w << 16);
}
__device__ __forceinline__ float bfh(unsigned w) {   // high bf16 of dword
    return __uint_as_float(w & 0xFFFF0000u);
}

// t0 = dis .* (X @ W^T), bf16, row stride 40 (80 B). One wave per 16 nodes.
__global__ __launch_bounds__(256) void transform_mfma(
    const float* __restrict__ x, const float* __restrict__ W,
    const float* __restrict__ dis, unsigned short* __restrict__ t0, int N)
{
    __shared__ uint4 Wl[3 * 4 * 64];        // B frags, bf16-packed: 12 KiB
    int t = threadIdx.x;
    for (int i = t; i < 3 * 4 * 64; i += 256) {
        int lane = i & 63;
        int kc = (i >> 6) & 3;
        int nt = i >> 8;
        int n = nt * 16 + (lane & 15);
        int k = kc * 32 + (lane >> 4) * 8;
        union { unsigned short s[8]; uint4 v; } u;
        #pragma unroll
        for (int j = 0; j < 8; ++j)
            u.s[j] = (n < N_CLASS) ? f2bf(W[n * N_FEAT + k + j]) : (unsigned short)0;
        Wl[i] = u.v;
    }
    __syncthreads();
    int wave = (blockIdx.x * blockDim.x + threadIdx.x) >> 6;
    int lane = threadIdx.x & 63;
    int ntile = (N + 15) / 16;
    if (wave >= ntile) return;
    int m = lane & 15, quad = lane >> 4;
    int row = wave * 16 + m;
    const short8* Wf = reinterpret_cast<const short8*>(Wl);
    floatx4 acc0 = {0.f, 0.f, 0.f, 0.f}, acc1 = acc0, acc2 = acc0;
    #pragma unroll
    for (int kc = 0; kc < 4; ++kc) {
        const float4* xr = reinterpret_cast<const float4*>(
            x + (size_t)row * N_FEAT + kc * 32 + quad * 8);
        float4 a0 = xr[0], a1 = xr[1];
        short8 af;
        af[0] = f2bf(a0.x); af[1] = f2bf(a0.y); af[2] = f2bf(a0.z); af[3] = f2bf(a0.w);
        af[4] = f2bf(a1.x); af[5] = f2bf(a1.y); af[6] = f2bf(a1.z); af[7] = f2bf(a1.w);
        short8 b0 = Wf[(0 * 4 + kc) * 64 + lane];
        short8 b1 = Wf[(1 * 4 + kc) * 64 + lane];
        short8 b2 = Wf[(2 * 4 + kc) * 64 + lane];
        acc0 = __builtin_amdgcn_mfma_f32_16x16x32_bf16(af, b0, acc0, 0, 0, 0);
        acc1 = __builtin_amdgcn_mfma_f32_16x16x32_bf16(af, b1, acc1, 0, 0, 0);
        acc2 = __builtin_amdgcn_mfma_f32_16x16x32_bf16(af, b2, acc2, 0, 0, 0);
    }
    #pragma unroll
    for (int r = 0; r < 4; ++r) {
        int rw = wave * 16 + quad * 4 + r;
        float ds = dis[rw];
        unsigned short* tr = t0 + (size_t)rw * N_CLASS;
        tr[m] = f2bf(ds * acc0[r]);
        tr[16 + m] = f2bf(ds * acc1[r]);
        if (m < 8) tr[32 + m] = f2bf(ds * acc2[r]);
    }
}

// --- gather core: 12 groups x 5 lanes x ushort8; a0..a7 = 8 classes/lane ----
// Unmasked add of one row quad-dword.
#define ACC_ADD(r)                                                             \
    a0 += bfl(r.x); a1 += bfh(r.x); a2 += bfl(r.y); a3 += bfh(r.y);            \
    a4 += bfl(r.z); a5 += bfh(r.z); a6 += bfl(r.w); a7 += bfh(r.w);
#define ACC_FMA(r, m)                                                          \
    a0 = fmaf(m, bfl(r.x), a0); a1 = fmaf(m, bfh(r.x), a1);                    \
    a2 = fmaf(m, bfl(r.y), a2); a3 = fmaf(m, bfh(r.y), a3);                    \
    a4 = fmaf(m, bfl(r.z), a4); a5 = fmaf(m, bfh(r.z), a5);                    \
    a6 = fmaf(m, bfl(r.w), a6); a7 = fmaf(m, bfh(r.w), a7);

// Shared gather+fold. After this block, lanes 0-4 hold classes [sl*8, sl*8+8).
#define GATHER12(tin)                                                          \
    int d = wave;                                                              \
    int g = lane / 5;                       /* 0..12 (lanes 60-63 ghost) */    \
    int sl = lane - g * 5;                  /* 0..4 */                         \
    int slo = sl << 4;                      /* byte offset within row */       \
    int e0 = starts[d], e1 = starts[d + 1];                                    \
    const char* tb = (const char*)(tin);                                       \
    float a0 = 0.f, a1 = 0.f, a2 = 0.f, a3 = 0.f;                              \
    float a4 = 0.f, a5 = 0.f, a6 = 0.f, a7 = 0.f;                              \
    if (lane < 5) {                         /* self term row d */              \
        uint4 r = *reinterpret_cast<const uint4*>(tb + d * 80 + slo);          \
        ACC_ADD(r)                                                             \
    }                                                                          \
    int gg = (g < 12) ? g : 0;              /* ghosts shadow group 0 */        \
    int e = e0;                                                                \
    for (; e + 24 <= e1; e += 24) {         /* unmasked: 2 gathers in flight */\
        int o1 = srcsB[e + gg];                                                \
        int o2 = srcsB[e + 12 + gg];                                           \
        uint4 r1 = *reinterpret_cast<const uint4*>(tb + (size_t)(unsigned)o1 + slo); \
        uint4 r2 = *reinterpret_cast<const uint4*>(tb + (size_t)(unsigned)o2 + slo); \
        ACC_ADD(r1)                                                            \
        ACC_ADD(r2)                                                            \
    }                                                                          \
    for (; e < e1; e += 12) {               /* masked tail, <=2 iters */       \
        int ee = e + gg;                                                       \
        int o1 = srcsB[min(ee, e1 - 1)];    /* e1>=1 always (deg>0 w.h.p.) */  \
        uint4 r1 = *reinterpret_cast<const uint4*>(tb + (size_t)(unsigned)o1 + slo); \
        float mk = (ee < e1 && g < 12) ? 1.0f : 0.0f;                          \
        ACC_FMA(r1, mk)                                                        \
    }                                                                          \
    /* fold 12 groups -> group 0 (lanes 0-4) */                                \
    a0 += __shfl(a0, lane + 30); a1 += __shfl(a1, lane + 30);                  \
    a2 += __shfl(a2, lane + 30); a3 += __shfl(a3, lane + 30);                  \
    a4 += __shfl(a4, lane + 30); a5 += __shfl(a5, lane + 30);                  \
    a6 += __shfl(a6, lane + 30); a7 += __shfl(a7, lane + 30);                  \
    a0 += __shfl(a0, lane + 15); a1 += __shfl(a1, lane + 15);                  \
    a2 += __shfl(a2, lane + 15); a3 += __shfl(a3, lane + 15);                  \
    a4 += __shfl(a4, lane + 15); a5 += __shfl(a5, lane + 15);                  \
    a6 += __shfl(a6, lane + 15); a7 += __shfl(a7, lane + 15);                  \
    {                                                                          \
        float u, v;                                                            \
        u = __shfl(a0, lane + 5); v = __shfl(a0, lane + 10); a0 += u + v;      \
        u = __shfl(a1, lane + 5); v = __shfl(a1, lane + 10); a1 += u + v;      \
        u = __shfl(a2, lane + 5); v = __shfl(a2, lane + 10); a2 += u + v;      \
        u = __shfl(a3, lane + 5); v = __shfl(a3, lane + 10); a3 += u + v;      \
        u = __shfl(a4, lane + 5); v = __shfl(a4, lane + 10); a4 += u + v;      \
        u = __shfl(a5, lane + 5); v = __shfl(a5, lane + 10); a5 += u + v;      \
        u = __shfl(a6, lane + 5); v = __shfl(a6, lane + 10); a6 += u + v;      \
        u = __shfl(a7, lane + 5); v = __shfl(a7, lane + 10); a7 += u + v;      \
    }

// Middle hop: tout[d] = bf16( dd^2 * (t[d] + sum t[src]) )
__global__ __launch_bounds__(256) void prop_hop_kernel(
    const unsigned short* __restrict__ tin, unsigned short* __restrict__ tout,
    const int* __restrict__ starts, const int* __restrict__ srcsB,
    const float* __restrict__ dis, int N)
{
    int wave = (blockIdx.x * blockDim.x + threadIdx.x) >> 6;
    int lane = threadIdx.x & 63;
    if (wave >= N) return;
    GATHER12(tin)
    if (lane < 5) {
        float dd = dis[d];
        float sc = dd * dd;
        unsigned w0 = ((unsigned)f2bf(sc * a0)) | ((unsigned)f2bf(sc * a1) << 16);
        unsigned w1 = ((unsigned)f2bf(sc * a2)) | ((unsigned)f2bf(sc * a3) << 16);
        unsigned w2 = ((unsigned)f2bf(sc * a4)) | ((unsigned)f2bf(sc * a5) << 16);
        unsigned w3 = ((unsigned)f2bf(sc * a6)) | ((unsigned)f2bf(sc * a7) << 16);
        uint4 o = make_uint4(w0, w1, w2, w3);
        *reinterpret_cast<uint4*>((char*)tout + d * 80 + slo) = o;
    }
}

// Final hop fused with bias + log_softmax (softmax across lanes 0-4 x 8).
__global__ __launch_bounds__(256) void prop_final_kernel(
    const unsigned short* __restrict__ tin, float* __restrict__ out,
    const int* __restrict__ starts, const int* __restrict__ srcsB,
    const float* __restrict__ dis, const float* __restrict__ bias, int N)
{
    int wave = (blockIdx.x * blockDim.x + threadIdx.x) >> 6;
    int lane = threadIdx.x & 63;
    if (wave >= N) return;
    GATHER12(tin)
    float dd = dis[d];
    float4 blo = reinterpret_cast<const float4*>(bias)[sl * 2];       // sl<5
    float4 bhi = reinterpret_cast<const float4*>(bias)[sl * 2 + 1];
    float v0 = dd * a0 + blo.x, v1 = dd * a1 + blo.y;
    float v2 = dd * a2 + blo.z, v3 = dd * a3 + blo.w;
    float v4 = dd * a4 + bhi.x, v5 = dd * a5 + bhi.y;
    float v6 = dd * a6 + bhi.z, v7 = dd * a7 + bhi.w;
    float mx = fmaxf(fmaxf(fmaxf(v0, v1), fmaxf(v2, v3)),
                     fmaxf(fmaxf(v4, v5), fmaxf(v6, v7)));
    if (lane >= 5) mx = -INFINITY;
    #pragma unroll
    for (int o = 4; o; o >>= 1) mx = fmaxf(mx, __shfl_xor(mx, o, 8));
    float sum = 0.f;
    if (lane < 5) {
        sum = expf(v0 - mx) + expf(v1 - mx) + expf(v2 - mx) + expf(v3 - mx)
            + expf(v4 - mx) + expf(v5 - mx) + expf(v6 - mx) + expf(v7 - mx);
    }
    #pragma unroll
    for (int o = 4; o; o >>= 1) sum += __shfl_xor(sum, o, 8);
    if (lane < 5) {
        float ls = mx + logf(sum);
        float* ro = out + (size_t)d * N_CLASS + sl * 8;
        *reinterpret_cast<float4*>(ro)     = make_float4(v0 - ls, v1 - ls, v2 - ls, v3 - ls);
        *reinterpret_cast<float4*>(ro + 4) = make_float4(v4 - ls, v5 - ls, v6 - ls, v7 - ls);
    }
}

// ---------------------------------------------------------------------------
extern "C" void kernel_launch(void* const* d_in, const int* in_sizes, int n_in,
                              void* d_out, int out_size, void* d_ws, size_t ws_size,
                              hipStream_t stream) {
    const float* feature = (const float*)d_in[0];   // [N, 128]
    const float* weight  = (const float*)d_in[1];   // [40, 128]
    const float* bias    = (const float*)d_in[2];   // [40]
    const int*   ei      = (const int*)d_in[3];     // [2, E] (int32 or int64 words)
    const int N = N_NODES;
    const int E = in_sizes[3] / 2;

    size_t off = 0;
    auto take = [&](size_t bytes) { size_t o = off; off += (bytes + 255) & ~(size_t)255; return o; };
    char* ws = (char*)d_ws;
    int*   flag      = (int*)  (ws + take(4));
    int*   bCount    = (int*)  (ws + take((size_t)NBALLOC * 4));
    int*   bStart    = (int*)  (ws + take((size_t)(NBALLOC + 1) * 4));
    int*   bCursor   = (int*)  (ws + take((size_t)NBALLOC * 4));
    int*   coarseCnt = (int*)  (ws + take((size_t)NCALLOC * 4));
    int*   starts    = (int*)  (ws + take((size_t)(N + 1) * 4));
    float* dis       = (float*)(ws + take((size_t)N * 4));
    // srcsB region also hosts tmpc (coarse records): tmpc dead before p4 writes srcsB
    size_t srcsBytes = (size_t)E * 4;
    size_t tmpcBytes = (size_t)NCALLOC * CCAP * 4;
    size_t bigBytes = srcsBytes > tmpcBytes ? srcsBytes : tmpcBytes;
    char* bigBase = ws + take(bigBytes);
    int* srcsB = (int*)bigBase;
    unsigned int* tmpc = (unsigned int*)bigBase;
    // t0+t1 (16 MB contiguous) also host tmp (fine records, E*4 = 12.8 MB)
    unsigned short* t0 = (unsigned short*)(ws + take((size_t)N * N_CLASS * 2));
    unsigned short* t1 = (unsigned short*)(ws + take((size_t)N * N_CLASS * 2));
    unsigned int* tmp = (unsigned int*)t0;

    // --- build CSR (two-level bucketed counting sort, pow2 ranges) ---
    detect_zero_kernel<<<1, 512, 0, stream>>>(ei, flag, bCount, coarseCnt);
    p3a_scatter<<<P3AGRID, 256, 0, stream>>>(ei, E, flag, bCount, coarseCnt, tmpc);
    p2_scan<<<1, NBALLOC, 0, stream>>>(bCount, bStart, bCursor, starts, E);
    p3b_scatter<<<NCUSED * 8, 256, 0, stream>>>(tmpc, coarseCnt, bCursor, tmp);
    p4_sort<<<NBUSED, 256, 0, stream>>>(tmp, bStart, starts, dis, srcsB, N);

    // --- transform (MFMA, pre-scaled bf16 rows) then 2 hops ---
    const int ntile = (N + 15) / 16;
    const int tblocks = (ntile * 64 + 255) / 256;
    transform_mfma<<<tblocks, 256, 0, stream>>>(feature, weight, dis, t0, N);
    const int nodeBlocks = (N * 64 + 255) / 256;           // one wave per node
    prop_hop_kernel<<<nodeBlocks, 256, 0, stream>>>(t0, t1, starts, srcsB, dis, N);
    prop_final_kernel<<<nodeBlocks, 256, 0, stream>>>(t1, (float*)d_out,
                                                      starts, srcsB, dis, bias, N);
}

// Round 10
// 329.079 us; speedup vs baseline: 1.2283x; 1.0143x over previous
//
#include <hip/hip_runtime.h>
#include <hip/hip_bf16.h>
#include <hip/hip_fp16.h>
#include <math.h>

// SGC: out = log_softmax( S^2 X W^T + b ), S = D^-1/2 (A+I) D^-1/2
// t0 = dis .* (X W^T) in *f16* (pre-scaled 80 B rows). One wave per dst node;
// gather = 12 groups x 5 lanes x 16B (one load covers 1/5 row = 8 f16),
// accumulation via v_pk_add_f16 (1 instr / 2 values), two banks for MLP.
// CSR via two-level bucketed counting sort with power-of-2 bucket ranges.

#define N_NODES 100000
#define N_FEAT  128
#define N_CLASS 40

#define RANGE   256           // dsts per fine bucket (pow2: dst>>8)
#define NBALLOC 512
#define NBUSED  391           // ceil(100000/256)
#define RANGE_C 2048          // dsts per coarse bucket (dst>>11)
#define NCALLOC 64
#define NCUSED  49            // ceil(100000/2048)
#define CAP     8704          // fine bucket LDS cap (mean 8192 + ~5.7 sigma)
#define CCAP    67072         // coarse region cap (mean 65536 + ~6 sigma)
#define P3AGRID 1024

typedef __attribute__((ext_vector_type(8))) short short8;   // 8 bf16 (4 VGPRs)
typedef __attribute__((ext_vector_type(4))) float floatx4;  // MFMA C/D

// ---------------------------------------------------------------------------
// Detect int32 vs int64 edge_index words; zero counters. 1 block x 512.
__global__ void detect_zero_kernel(const int* __restrict__ ei, int* __restrict__ flag,
                                   int* __restrict__ bucketCount,
                                   int* __restrict__ coarseCnt) {
    int t = threadIdx.x;
    if (t < NBALLOC) bucketCount[t] = 0;
    if (t < NCALLOC) coarseCnt[t] = 0;
    if (t < 64) {
        int nz = (ei[2 * t + 1] != 0) ? 1 : 0;
        unsigned long long b = __ballot(nz);
        if (t == 0) *flag = (b == 0ull) ? 1 : 0;   // 1 => int64 layout
    }
}

__device__ __forceinline__ int edge_word(const int* ei, int elem, int is64) {
    return is64 ? ei[2 * elem] : ei[elem];
}

// P3a: scatter packed records (dstLocalCoarse<<17 | src) into per-block dense
// runs within coarse regions; simultaneously build the fine histogram.
__global__ __launch_bounds__(256) void p3a_scatter(
    const int* __restrict__ ei, int E, const int* __restrict__ flag,
    int* __restrict__ bucketCount, int* __restrict__ coarseCnt,
    unsigned int* __restrict__ tmpc)
{
    __shared__ int hf[NBALLOC];
    __shared__ int hc[NCALLOC];
    __shared__ int basec[NCALLOC];
    __shared__ int curc[NCALLOC];
    int t = threadIdx.x;
    for (int i = t; i < NBALLOC; i += 256) hf[i] = 0;
    if (t < NCALLOC) hc[t] = 0;
    __syncthreads();
    int is64 = *flag;
    int per = (E + gridDim.x - 1) / gridDim.x;
    int e0 = blockIdx.x * per;
    int e1 = min(E, e0 + per);
    for (int e = e0 + t; e < e1; e += 256) {
        int c = edge_word(ei, E + e, is64);
        atomicAdd(&hf[c >> 8], 1);
        atomicAdd(&hc[c >> 11], 1);
    }
    __syncthreads();
    if (t < NCALLOC) {
        basec[t] = hc[t] ? atomicAdd(&coarseCnt[t], hc[t]) : 0;
        curc[t] = 0;
    }
    for (int i = t; i < NBALLOC; i += 256)
        if (hf[i]) atomicAdd(&bucketCount[i], hf[i]);
    __syncthreads();
    for (int e = e0 + t; e < e1; e += 256) {
        int c = edge_word(ei, E + e, is64);
        int r = edge_word(ei, e, is64);
        int cb = c >> 11;
        int p = basec[cb] + atomicAdd(&curc[cb], 1);
        if (p < CCAP)
            tmpc[(size_t)cb * CCAP + p] = ((unsigned)(c & 2047) << 17) | (unsigned)r;
    }
}

// P2: scan fine counts -> bucketStart/bucketCursor; starts[N]=E.
__global__ __launch_bounds__(NBALLOC) void p2_scan(
    const int* __restrict__ bucketCount, int* __restrict__ bucketStart,
    int* __restrict__ bucketCursor, int* __restrict__ starts, int E)
{
    __shared__ int s[NBALLOC];
    int t = threadIdx.x;
    int v = bucketCount[t];
    s[t] = v;
    __syncthreads();
    for (int o = 1; o < NBALLOC; o <<= 1) {
        int y = (t >= o) ? s[t - o] : 0;
        __syncthreads();
        s[t] += y;
        __syncthreads();
    }
    int incl = s[t], excl = incl - v;
    bucketStart[t] = excl;
    bucketCursor[t] = excl;
    if (t == NBALLOC - 1) { bucketStart[NBALLOC] = incl; starts[N_NODES] = E; }
}

// P3b: 8 blocks per coarse bucket; re-scatter into its 8 fine buckets.
__global__ __launch_bounds__(256) void p3b_scatter(
    const unsigned int* __restrict__ tmpc, const int* __restrict__ coarseCnt,
    int* __restrict__ bucketCursor, unsigned int* __restrict__ tmp)
{
    __shared__ int fh[8];
    __shared__ int fb[8];
    __shared__ int fc[8];
    int cb = blockIdx.x >> 3;
    int j = blockIdx.x & 7;
    int t = threadIdx.x;
    int cnt = coarseCnt[cb];
    if (cnt > CCAP) cnt = CCAP;
    int chunk = (cnt + 7) >> 3;
    int r0 = j * chunk;
    int r1 = min(cnt, r0 + chunk);
    if (t < 8) fh[t] = 0;
    __syncthreads();
    const unsigned int* rec = tmpc + (size_t)cb * CCAP;
    for (int i = r0 + t; i < r1; i += 256) {
        int dlc = (int)(rec[i] >> 17);
        atomicAdd(&fh[dlc >> 8], 1);
    }
    __syncthreads();
    if (t < 8) {
        fb[t] = fh[t] ? atomicAdd(&bucketCursor[cb * 8 + t], fh[t]) : 0;
        fc[t] = 0;
    }
    __syncthreads();
    for (int i = r0 + t; i < r1; i += 256) {
        unsigned v = rec[i];
        int dlc = (int)(v >> 17);
        unsigned src = v & 0x1FFFFu;
        int fi = dlc >> 8;
        int dlf = dlc & 255;
        int p = fb[fi] + atomicAdd(&fc[fi], 1);
        tmp[p] = ((unsigned)dlf << 24) | src;
    }
}

// P4: per-fine-bucket LDS counting sort -> starts, dis, srcsB (byte offsets,
// src*80, coalesced). No rec[] cache: tmp is read twice (streaming).
__global__ __launch_bounds__(256) void p4_sort(
    const unsigned int* __restrict__ tmp, const int* __restrict__ bucketStart,
    int* __restrict__ starts, float* __restrict__ dis, int* __restrict__ srcsB, int N)
{
    __shared__ int srt[CAP];
    __shared__ int hist[256];
    __shared__ int sc[256];
    __shared__ int cur[256];
    int b = blockIdx.x, t = threadIdx.x;
    int g0 = b * RANGE;
    int gcnt = N - g0;
    if (gcnt > RANGE) gcnt = RANGE;
    int base = bucketStart[b];
    int n = bucketStart[b + 1] - base;
    hist[t] = 0;
    __syncthreads();
    for (int i = t; i < n; i += 256)
        atomicAdd(&hist[tmp[base + i] >> 24], 1);
    __syncthreads();
    int hv = hist[t];
    sc[t] = hv;
    __syncthreads();
    for (int o = 1; o < 256; o <<= 1) {
        int y = (t >= o) ? sc[t - o] : 0;
        __syncthreads();
        sc[t] += y;
        __syncthreads();
    }
    int excl = sc[t] - hv;
    if (t < gcnt) {
        starts[g0 + t] = base + excl;
        dis[g0 + t] = rsqrtf((float)(hv + 1));   // +1 self-loop
    }
    cur[t] = excl;
    __syncthreads();
    if (n <= CAP) {
        for (int i = t; i < n; i += 256) {
            unsigned v = tmp[base + i];
            int p = atomicAdd(&cur[v >> 24], 1);
            srt[p] = (int)(v & 0xFFFFFFu) * 80;   // pre-scaled byte offset
        }
        __syncthreads();
        for (int i = t; i < n; i += 256) srcsB[base + i] = srt[i];
    } else {
        // overflow fallback (statistically never taken)
        for (int i = t; i < n; i += 256) {
            unsigned v = tmp[base + i];
            int p = atomicAdd(&cur[v >> 24], 1);
            srcsB[base + p] = (int)(v & 0xFFFFFFu) * 80;
        }
    }
}

// ---------------------------------------------------------------------------
__device__ __forceinline__ unsigned short f2bf(float f) {   // RTN f32 -> bf16
    unsigned u = __float_as_uint(f);
    unsigned r = u + 0x7FFFu + ((u >> 16) & 1u);
    return (unsigned short)(r >> 16);
}
__device__ __forceinline__ __half2 u2h(unsigned w) {
    union { unsigned u; __half2 h; } c; c.u = w; return c.h;
}
__device__ __forceinline__ unsigned h2u(__half2 h) {
    union { unsigned u; __half2 h; } c; c.h = h; return c.u;
}

// t0 = dis .* (X @ W^T), f16, row stride 40 (80 B). One wave per 16 nodes.
// MFMA on bf16 inputs (f32 accumulate), output stored f16.
__global__ __launch_bounds__(256) void transform_mfma(
    const float* __restrict__ x, const float* __restrict__ W,
    const float* __restrict__ dis, unsigned short* __restrict__ t0, int N)
{
    __shared__ uint4 Wl[3 * 4 * 64];        // B frags, bf16-packed: 12 KiB
    int t = threadIdx.x;
    for (int i = t; i < 3 * 4 * 64; i += 256) {
        int lane = i & 63;
        int kc = (i >> 6) & 3;
        int nt = i >> 8;
        int n = nt * 16 + (lane & 15);
        int k = kc * 32 + (lane >> 4) * 8;
        union { unsigned short s[8]; uint4 v; } u;
        #pragma unroll
        for (int j = 0; j < 8; ++j)
            u.s[j] = (n < N_CLASS) ? f2bf(W[n * N_FEAT + k + j]) : (unsigned short)0;
        Wl[i] = u.v;
    }
    __syncthreads();
    int wave = (blockIdx.x * blockDim.x + threadIdx.x) >> 6;
    int lane = threadIdx.x & 63;
    int ntile = (N + 15) / 16;
    if (wave >= ntile) return;
    int m = lane & 15, quad = lane >> 4;
    int row = wave * 16 + m;
    const short8* Wf = reinterpret_cast<const short8*>(Wl);
    floatx4 acc0 = {0.f, 0.f, 0.f, 0.f}, acc1 = acc0, acc2 = acc0;
    #pragma unroll
    for (int kc = 0; kc < 4; ++kc) {
        const float4* xr = reinterpret_cast<const float4*>(
            x + (size_t)row * N_FEAT + kc * 32 + quad * 8);
        float4 a0 = xr[0], a1 = xr[1];
        short8 af;
        af[0] = f2bf(a0.x); af[1] = f2bf(a0.y); af[2] = f2bf(a0.z); af[3] = f2bf(a0.w);
        af[4] = f2bf(a1.x); af[5] = f2bf(a1.y); af[6] = f2bf(a1.z); af[7] = f2bf(a1.w);
        short8 b0 = Wf[(0 * 4 + kc) * 64 + lane];
        short8 b1 = Wf[(1 * 4 + kc) * 64 + lane];
        short8 b2 = Wf[(2 * 4 + kc) * 64 + lane];
        acc0 = __builtin_amdgcn_mfma_f32_16x16x32_bf16(af, b0, acc0, 0, 0, 0);
        acc1 = __builtin_amdgcn_mfma_f32_16x16x32_bf16(af, b1, acc1, 0, 0, 0);
        acc2 = __builtin_amdgcn_mfma_f32_16x16x32_bf16(af, b2, acc2, 0, 0, 0);
    }
    #pragma unroll
    for (int r = 0; r < 4; ++r) {
        int rw = wave * 16 + quad * 4 + r;
        float ds = dis[rw];
        unsigned short* tr = t0 + (size_t)rw * N_CLASS;
        tr[m] = __half_as_ushort(__float2half(ds * acc0[r]));
        tr[16 + m] = __half_as_ushort(__float2half(ds * acc1[r]));
        if (m < 8) tr[32 + m] = __half_as_ushort(__float2half(ds * acc2[r]));
    }
}

// 12-group fold: groups 0..11 (lanes 0-59) summed into lanes 0-4, packed f16.
__device__ __forceinline__ __half2 foldh(__half2 a, int lane) {
    a = __hadd2(a, u2h((unsigned)__shfl((int)h2u(a), lane + 30)));
    a = __hadd2(a, u2h((unsigned)__shfl((int)h2u(a), lane + 15)));
    __half2 u = u2h((unsigned)__shfl((int)h2u(a), lane + 5));
    __half2 v = u2h((unsigned)__shfl((int)h2u(a), lane + 10));
    return __hadd2(__hadd2(a, u), v);
}

// Shared gather: 12 groups x 5 lanes x 16B; packed-f16 accumulate, 2 banks.
// After fold, lanes 0-4 hold classes [sl*8, sl*8+8) in A0..A3 (lo,hi pairs).
#define GATHER12H(tin)                                                         \
    int d = wave;                                                              \
    int g = lane / 5;                       /* 0..12 (lanes 60-63 ghost) */    \
    int sl = lane - g * 5;                  /* 0..4 */                         \
    int slo = sl << 4;                      /* byte offset within row */       \
    int e0 = starts[d], e1 = starts[d + 1];                                    \
    const char* tb = (const char*)(tin);                                       \
    __half2 z2 = u2h(0u);                                                      \
    __half2 A0 = z2, A1 = z2, A2 = z2, A3 = z2;                                \
    __half2 B0 = z2, B1 = z2, B2 = z2, B3 = z2;                                \
    if (lane < 5) {                         /* self term row d */              \
        uint4 r = *reinterpret_cast<const uint4*>(tb + d * 80 + slo);          \
        A0 = u2h(r.x); A1 = u2h(r.y); A2 = u2h(r.z); A3 = u2h(r.w);            \
    }                                                                          \
    int gg = (g < 12) ? g : 0;              /* ghosts shadow group 0 */        \
    int e = e0;                                                                \
    for (; e + 24 <= e1; e += 24) {         /* unmasked: 2 gathers in flight */\
        int o1 = srcsB[e + gg];                                                \
        int o2 = srcsB[e + 12 + gg];                                           \
        uint4 r1 = *reinterpret_cast<const uint4*>(tb + (size_t)(unsigned)o1 + slo); \
        uint4 r2 = *reinterpret_cast<const uint4*>(tb + (size_t)(unsigned)o2 + slo); \
        A0 = __hadd2(A0, u2h(r1.x)); A1 = __hadd2(A1, u2h(r1.y));              \
        A2 = __hadd2(A2, u2h(r1.z)); A3 = __hadd2(A3, u2h(r1.w));              \
        B0 = __hadd2(B0, u2h(r2.x)); B1 = __hadd2(B1, u2h(r2.y));              \
        B2 = __hadd2(B2, u2h(r2.z)); B3 = __hadd2(B3, u2h(r2.w));              \
    }                                                                          \
    for (; e < e1; e += 12) {               /* masked tail, <=2 iters */       \
        int ee = e + gg;                                                       \
        int o1 = srcsB[min(ee, e1 - 1)];                                       \
        uint4 r1 = *reinterpret_cast<const uint4*>(tb + (size_t)(unsigned)o1 + slo); \
        if (!(ee < e1 && g < 12)) { r1.x = 0u; r1.y = 0u; r1.z = 0u; r1.w = 0u; } \
        A0 = __hadd2(A0, u2h(r1.x)); A1 = __hadd2(A1, u2h(r1.y));              \
        A2 = __hadd2(A2, u2h(r1.z)); A3 = __hadd2(A3, u2h(r1.w));              \
    }                                                                          \
    A0 = __hadd2(A0, B0); A1 = __hadd2(A1, B1);                                \
    A2 = __hadd2(A2, B2); A3 = __hadd2(A3, B3);                                \
    A0 = foldh(A0, lane); A1 = foldh(A1, lane);                                \
    A2 = foldh(A2, lane); A3 = foldh(A3, lane);

// Middle hop: tout[d] = f16( dd^2 * (t[d] + sum t[src]) )
__global__ __launch_bounds__(256) void prop_hop_kernel(
    const unsigned short* __restrict__ tin, unsigned short* __restrict__ tout,
    const int* __restrict__ starts, const int* __restrict__ srcsB,
    const float* __restrict__ dis, int N)
{
    int wave = (blockIdx.x * blockDim.x + threadIdx.x) >> 6;
    int lane = threadIdx.x & 63;
    if (wave >= N) return;
    GATHER12H(tin)
    if (lane < 5) {
        float dd = dis[d];
        float sc = dd * dd;
        float2 f0 = __half22float2(A0), f1 = __half22float2(A1);
        float2 f2 = __half22float2(A2), f3 = __half22float2(A3);
        uint4 o;
        o.x = h2u(__floats2half2_rn(sc * f0.x, sc * f0.y));
        o.y = h2u(__floats2half2_rn(sc * f1.x, sc * f1.y));
        o.z = h2u(__floats2half2_rn(sc * f2.x, sc * f2.y));
        o.w = h2u(__floats2half2_rn(sc * f3.x, sc * f3.y));
        *reinterpret_cast<uint4*>((char*)tout + d * 80 + slo) = o;
    }
}

// Final hop fused with bias + log_softmax (softmax across lanes 0-4 x 8).
__global__ __launch_bounds__(256) void prop_final_kernel(
    const unsigned short* __restrict__ tin, float* __restrict__ out,
    const int* __restrict__ starts, const int* __restrict__ srcsB,
    const float* __restrict__ dis, const float* __restrict__ bias, int N)
{
    int wave = (blockIdx.x * blockDim.x + threadIdx.x) >> 6;
    int lane = threadIdx.x & 63;
    if (wave >= N) return;
    GATHER12H(tin)
    float dd = dis[d];
    float2 f0 = __half22float2(A0), f1 = __half22float2(A1);
    float2 f2 = __half22float2(A2), f3 = __half22float2(A3);
    float4 blo = reinterpret_cast<const float4*>(bias)[sl * 2];       // sl<5
    float4 bhi = reinterpret_cast<const float4*>(bias)[sl * 2 + 1];
    float v0 = dd * f0.x + blo.x, v1 = dd * f0.y + blo.y;
    float v2 = dd * f1.x + blo.z, v3 = dd * f1.y + blo.w;
    float v4 = dd * f2.x + bhi.x, v5 = dd * f2.y + bhi.y;
    float v6 = dd * f3.x + bhi.z, v7 = dd * f3.y + bhi.w;
    float mx = fmaxf(fmaxf(fmaxf(v0, v1), fmaxf(v2, v3)),
                     fmaxf(fmaxf(v4, v5), fmaxf(v6, v7)));
    if (lane >= 5) mx = -INFINITY;
    #pragma unroll
    for (int o = 4; o; o >>= 1) mx = fmaxf(mx, __shfl_xor(mx, o, 8));
    float sum = 0.f;
    if (lane < 5) {
        sum = expf(v0 - mx) + expf(v1 - mx) + expf(v2 - mx) + expf(v3 - mx)
            + expf(v4 - mx) + expf(v5 - mx) + expf(v6 - mx) + expf(v7 - mx);
    }
    #pragma unroll
    for (int o = 4; o; o >>= 1) sum += __shfl_xor(sum, o, 8);
    if (lane < 5) {
        float ls = mx + logf(sum);
        float* ro = out + (size_t)d * N_CLASS + sl * 8;
        *reinterpret_cast<float4*>(ro)     = make_float4(v0 - ls, v1 - ls, v2 - ls, v3 - ls);
        *reinterpret_cast<float4*>(ro + 4) = make_float4(v4 - ls, v5 - ls, v6 - ls, v7 - ls);
    }
}

// ---------------------------------------------------------------------------
extern "C" void kernel_launch(void* const* d_in, const int* in_sizes, int n_in,
                              void* d_out, int out_size, void* d_ws, size_t ws_size,
                              hipStream_t stream) {
    const float* feature = (const float*)d_in[0];   // [N, 128]
    const float* weight  = (const float*)d_in[1];   // [40, 128]
    const float* bias    = (const float*)d_in[2];   // [40]
    const int*   ei      = (const int*)d_in[3];     // [2, E] (int32 or int64 words)
    const int N = N_NODES;
    const int E = in_sizes[3] / 2;

    size_t off = 0;
    auto take = [&](size_t bytes) { size_t o = off; off += (bytes + 255) & ~(size_t)255; return o; };
    char* ws = (char*)d_ws;
    int*   flag      = (int*)  (ws + take(4));
    int*   bCount    = (int*)  (ws + take((size_t)NBALLOC * 4));
    int*   bStart    = (int*)  (ws + take((size_t)(NBALLOC + 1) * 4));
    int*   bCursor   = (int*)  (ws + take((size_t)NBALLOC * 4));
    int*   coarseCnt = (int*)  (ws + take((size_t)NCALLOC * 4));
    int*   starts    = (int*)  (ws + take((size_t)(N + 1) * 4));
    float* dis       = (float*)(ws + take((size_t)N * 4));
    // srcsB region also hosts tmpc (coarse records): tmpc dead before p4 writes srcsB
    size_t srcsBytes = (size_t)E * 4;
    size_t tmpcBytes = (size_t)NCALLOC * CCAP * 4;
    size_t bigBytes = srcsBytes > tmpcBytes ? srcsBytes : tmpcBytes;
    char* bigBase = ws + take(bigBytes);
    int* srcsB = (int*)bigBase;
    unsigned int* tmpc = (unsigned int*)bigBase;
    // t0+t1 (16 MB contiguous) also host tmp (fine records, E*4 = 12.8 MB)
    unsigned short* t0 = (unsigned short*)(ws + take((size_t)N * N_CLASS * 2));
    unsigned short* t1 = (unsigned short*)(ws + take((size_t)N * N_CLASS * 2));
    unsigned int* tmp = (unsigned int*)t0;

    // --- build CSR (two-level bucketed counting sort, pow2 ranges) ---
    detect_zero_kernel<<<1, 512, 0, stream>>>(ei, flag, bCount, coarseCnt);
    p3a_scatter<<<P3AGRID, 256, 0, stream>>>(ei, E, flag, bCount, coarseCnt, tmpc);
    p2_scan<<<1, NBALLOC, 0, stream>>>(bCount, bStart, bCursor, starts, E);
    p3b_scatter<<<NCUSED * 8, 256, 0, stream>>>(tmpc, coarseCnt, bCursor, tmp);
    p4_sort<<<NBUSED, 256, 0, stream>>>(tmp, bStart, starts, dis, srcsB, N);

    // --- transform (MFMA, pre-scaled f16 rows) then 2 hops ---
    const int ntile = (N + 15) / 16;
    const int tblocks = (ntile * 64 + 255) / 256;
    transform_mfma<<<tblocks, 256, 0, stream>>>(feature, weight, dis, t0, N);
    const int nodeBlocks = (N * 64 + 255) / 256;           // one wave per node
    prop_hop_kernel<<<nodeBlocks, 256, 0, stream>>>(t0, t1, starts, srcsB, dis, N);
    prop_final_kernel<<<nodeBlocks, 256, 0, stream>>>(t1, (float*)d_out,
                                                      starts, srcsB, dis, bias, N);
}